// Round 1
// baseline (442.906 us; speedup 1.0000x reference)
//
#include <hip/hip_runtime.h>

#define R   3
#define TW  64
#define TH  64
#define HALO (2*R)
#define LW  (TW + HALO)   // 70
#define LH  (TH + HALO)   // 70
#define PITCH 72          // padded LDS row pitch (floats)

__global__ __launch_bounds__(256) void bilateral_kernel(
    const float* __restrict__ in, float* __restrict__ out, int H, int W)
{
    __shared__ float tile[LH * PITCH];

    const int tx = threadIdx.x;           // 0..63
    const int ty = threadIdx.y;           // 0..3
    const int gx0 = blockIdx.x * TW;
    const int gy0 = blockIdx.y * TH;
    const size_t plane_off = (size_t)blockIdx.z * H * W;
    const float* __restrict__ p = in + plane_off;
    float* __restrict__ q = out + plane_off;

    // ---- Load 70x70 halo tile with edge clamp (coalesced rows) ----
    for (int row = ty; row < LH; row += 4) {
        int gy = gy0 + row - R;
        gy = min(max(gy, 0), H - 1);
        const float* rp = p + (size_t)gy * W;
        #pragma unroll
        for (int col = tx; col < LW; col += 64) {
            int gx = gx0 + col - R;
            gx = min(max(gx, 0), W - 1);
            tile[row * PITCH + col] = rp[gx];
        }
    }
    __syncthreads();

    const float kc = -50.0f;   // -1/(2*sigma_c^2), sigma_c = 0.1

    // ---- Each thread computes TH/4 = 16 pixels (rows ty, ty+4, ...) ----
    for (int j = 0; j < TH / 4; ++j) {
        const int oy = ty + 4 * j;                 // output row within tile
        const float x = tile[(oy + R) * PITCH + (tx + R)];   // center value
        float num = 0.0f, den = 0.0f;

        #pragma unroll
        for (int dy = 0; dy < 7; ++dy) {
            #pragma unroll
            for (int dx = 0; dx < 7; ++dx) {
                // spatial term folded in as a compile-time constant:
                // sarg = -((dy-3)^2 + (dx-3)^2) / (2*3^2)
                const float sarg = -(float)((dy - R) * (dy - R) +
                                            (dx - R) * (dx - R)) * (1.0f / 18.0f);
                const float s = tile[(oy + dy) * PITCH + (tx + dx)];
                const float d = s - x;
                const float arg = fmaf(d * d, kc, sarg);
                const float w = __expf(arg);       // v_exp_f32
                num = fmaf(w, s, num);
                den += w;
            }
        }
        q[(size_t)(gy0 + oy) * W + gx0 + tx] = num / den;
    }
}

extern "C" void kernel_launch(void* const* d_in, const int* in_sizes, int n_in,
                              void* d_out, int out_size, void* d_ws, size_t ws_size,
                              hipStream_t stream)
{
    const float* in = (const float*)d_in[0];
    float* out = (float*)d_out;

    const int H = 1024, W = 1024;
    const int planes = in_sizes[0] / (H * W);      // 16 * 3 = 48

    dim3 grid(W / TW, H / TH, planes);             // 16 x 16 x 48
    dim3 block(64, 4, 1);
    bilateral_kernel<<<grid, block, 0, stream>>>(in, out, H, W);
}

// Round 2
// 373.546 us; speedup vs baseline: 1.1857x; 1.1857x over previous
//
#include <hip/hip_runtime.h>

#define R   3
#define TW  64
#define TH  64
#define LW  (TW + 2*R)   // 70
#define LH  (TH + 2*R)   // 70
#define PITCH 72         // padded LDS row pitch (floats)

__device__ __forceinline__ float fast_exp2(float x) {
#if __has_builtin(__builtin_amdgcn_exp2f)
    return __builtin_amdgcn_exp2f(x);   // single v_exp_f32
#else
    return exp2f(x);
#endif
}

__global__ __launch_bounds__(256) void bilateral_kernel(
    const float* __restrict__ in, float* __restrict__ out, int H, int W)
{
    __shared__ float tile[LH * PITCH];

    const int tx = threadIdx.x;           // 0..63 (one wave per ty)
    const int ty = threadIdx.y;           // 0..3
    const int gx0 = blockIdx.x * TW;
    const int gy0 = blockIdx.y * TH;
    const size_t plane_off = (size_t)blockIdx.z * H * W;
    const float* __restrict__ p = in + plane_off;
    float* __restrict__ q = out + plane_off;

    // ---- Load 70x70 halo tile with edge clamp (coalesced rows) ----
    for (int row = ty; row < LH; row += 4) {
        int gy = min(max(gy0 + row - R, 0), H - 1);
        const float* rp = p + (size_t)gy * W;
        #pragma unroll
        for (int col = tx; col < LW; col += 64) {
            int gx = min(max(gx0 + col - R, 0), W - 1);
            tile[row * PITCH + col] = rp[gx];
        }
    }
    __syncthreads();

    const float LOG2E = 1.4426950408889634f;
    const float KC2   = -50.0f * LOG2E;        // color coeff pre-scaled by log2e
    const float SSC   = LOG2E / 18.0f;         // spatial coeff pre-scaled

    // Each wave (ty) owns a contiguous 16-row band; process 2 rows per step.
    for (int j = 0; j < 8; ++j) {
        const int oy = ty * 16 + 2 * j;        // tile-relative output rows oy, oy+1
        const float x0 = tile[(oy + R) * PITCH + tx + R];
        const float x1 = tile[(oy + 1 + R) * PITCH + tx + R];
        // arg = KC2*(s-x)^2 + sarg2 = s*(KC2*s + b) + (KC2*x^2 + sarg2)
        const float b0  = -2.0f * KC2 * x0;
        const float cb0 = KC2 * x0 * x0;
        const float b1  = -2.0f * KC2 * x1;
        const float cb1 = KC2 * x1 * x1;

        float num0 = 0.f, den0 = 0.f, num1 = 0.f, den1 = 0.f;

        #pragma unroll
        for (int ry = 0; ry < 8; ++ry) {       // union of the two 7-row windows
            #pragma unroll
            for (int dx = 0; dx < 7; ++dx) {
                const float s = tile[(oy + ry) * PITCH + tx + dx];
                if (ry < 7) {                  // tap for center 0 (dy = ry)
                    const float sarg2 = -(float)((ry - 3) * (ry - 3) +
                                                 (dx - 3) * (dx - 3)) * SSC;
                    const float t   = fmaf(KC2, s, b0);
                    const float arg = fmaf(s, t, cb0 + sarg2);   // cb0+sarg2 CSE'd (10 values)
                    const float w   = fast_exp2(arg);
                    num0 = fmaf(w, s, num0);
                    den0 += w;
                }
                if (ry >= 1) {                 // tap for center 1 (dy = ry-1)
                    const float sarg2 = -(float)((ry - 4) * (ry - 4) +
                                                 (dx - 3) * (dx - 3)) * SSC;
                    const float t   = fmaf(KC2, s, b1);
                    const float arg = fmaf(s, t, cb1 + sarg2);
                    const float w   = fast_exp2(arg);
                    num1 = fmaf(w, s, num1);
                    den1 += w;
                }
            }
        }

        const float r0 = __builtin_amdgcn_rcpf(den0);   // den in [1,49], 1-ulp rcp fine
        const float r1 = __builtin_amdgcn_rcpf(den1);
        q[(size_t)(gy0 + oy)     * W + gx0 + tx] = num0 * r0;
        q[(size_t)(gy0 + oy + 1) * W + gx0 + tx] = num1 * r1;
    }
}

extern "C" void kernel_launch(void* const* d_in, const int* in_sizes, int n_in,
                              void* d_out, int out_size, void* d_ws, size_t ws_size,
                              hipStream_t stream)
{
    const float* in = (const float*)d_in[0];
    float* out = (float*)d_out;

    const int H = 1024, W = 1024;
    const int planes = in_sizes[0] / (H * W);      // 16 * 3 = 48

    dim3 grid(W / TW, H / TH, planes);             // 16 x 16 x 48
    dim3 block(64, 4, 1);
    bilateral_kernel<<<grid, block, 0, stream>>>(in, out, H, W);
}

// Round 3
// 350.115 us; speedup vs baseline: 1.2650x; 1.0669x over previous
//
#include <hip/hip_runtime.h>

typedef float v2f __attribute__((ext_vector_type(2)));
typedef float v4f __attribute__((ext_vector_type(4)));

#define RAD 3
#define TW  256              // tile width  (64 lanes x 4 cols)
#define TH  16               // tile height (4 waves x 4 rows, 2 rows/step)
#define LROWS (TH + 2*RAD)   // 22
#define PITCH 264            // LDS row pitch in floats; covers global [gx0-4, gx0+260)

__device__ __forceinline__ float fexp2(float x) {
#if __has_builtin(__builtin_amdgcn_exp2f)
    return __builtin_amdgcn_exp2f(x);
#else
    return exp2f(x);
#endif
}

#define LOG2E 1.4426950408889634f
#define KC2   (-50.0f * LOG2E)          // color coeff, pre-scaled by log2(e)
#define SSC   (LOG2E / 18.0f)           // spatial coeff, pre-scaled
#define SARG(dy,dx) (-(float)(((dy)-3)*((dy)-3) + ((dx)-3)*((dx)-3)) * SSC)

__global__ __launch_bounds__(256) void bilateral_kernel(
    const float* __restrict__ in, float* __restrict__ out, int H, int W)
{
    __shared__ float tile[LROWS * PITCH];

    const int tx = threadIdx.x;              // 0..63
    const int ty = threadIdx.y;              // 0..3 (wave id)
    const int gx0 = blockIdx.x * TW;
    const int gy0 = blockIdx.y * TH;
    const size_t plane = (size_t)blockIdx.z * H * W;
    const float* __restrict__ p = in + plane;
    float* __restrict__ q = out + plane;

    // ---- Stage 22 x 264 tile (tile col c <-> global col gx0 + c - 4) ----
    const bool xedge = (blockIdx.x == 0) || (blockIdx.x == gridDim.x - 1);
    for (int r = ty; r < LROWS; r += 4) {
        const int gy = min(max(gy0 + r - RAD, 0), H - 1);
        const float* rp = p + (size_t)gy * W;
        for (int qd = tx; qd < PITCH / 4; qd += 64) {
            const int gc = gx0 - 4 + 4 * qd;
            v4f val;
            if (!xedge || (gc >= 0 && gc + 3 < W)) {
                val = *reinterpret_cast<const v4f*>(rp + gc);
            } else {
                #pragma unroll
                for (int e = 0; e < 4; ++e) {
                    const int c = min(max(gc + e, 0), W - 1);
                    val[e] = rp[c];
                }
            }
            *reinterpret_cast<v4f*>(&tile[r * PITCH + 4 * qd]) = val;
        }
    }
    __syncthreads();

    const v2f KC2v = {KC2, KC2};

    // Each wave owns rows [4*ty, 4*ty+4); 2 steps of a vertical pixel pair.
    #pragma unroll 1
    for (int step = 0; step < 2; ++step) {
        const int ory = ty * 4 + step * 2;   // tile-relative output rows ory, ory+1

        // Center values: tile rows ory+3 / ory+4, tile cols 4tx+4 .. 4tx+7
        const v4f xc0 = *reinterpret_cast<const v4f*>(&tile[(ory + 3) * PITCH + 4 * tx + 4]);
        const v4f xc1 = *reinterpret_cast<const v4f*>(&tile[(ory + 4) * PITCH + 4 * tx + 4]);

        v2f b2[4], cb2[4], num2[4], den2[4];
        #pragma unroll
        for (int pp = 0; pp < 4; ++pp) {
            const float xa = xc0[pp], xb = xc1[pp];
            b2[pp]  = (v2f){-2.0f * KC2 * xa, -2.0f * KC2 * xb};
            cb2[pp] = (v2f){KC2 * xa * xa,    KC2 * xb * xb};
            num2[pp] = (v2f){0.f, 0.f};
            den2[pp] = (v2f){0.f, 0.f};
        }

        #pragma unroll
        for (int rr = 0; rr < 8; ++rr) {     // union of the two 7-row windows
            const float* rowp = &tile[(ory + rr) * PITCH + 4 * tx];
            const v4f ra = *reinterpret_cast<const v4f*>(rowp);
            const v4f rb = *reinterpret_cast<const v4f*>(rowp + 4);
            const v4f rc = *reinterpret_cast<const v4f*>(rowp + 8);
            const float v[12] = {ra.x, ra.y, ra.z, ra.w,
                                 rb.x, rb.y, rb.z, rb.w,
                                 rc.x, rc.y, rc.z, rc.w};

            if (rr == 0) {                   // only center0, dy = 0 (scalar)
                #pragma unroll
                for (int pp = 0; pp < 4; ++pp)
                    #pragma unroll
                    for (int dx = 0; dx < 7; ++dx) {
                        const float s = v[1 + pp + dx];
                        const float t = fmaf(KC2, s, b2[pp].x);
                        const float w = fexp2(fmaf(s, t, cb2[pp].x + SARG(0, dx)));
                        num2[pp].x = fmaf(w, s, num2[pp].x);
                        den2[pp].x += w;
                    }
            } else if (rr == 7) {            // only center1, dy = 6 (scalar)
                #pragma unroll
                for (int pp = 0; pp < 4; ++pp)
                    #pragma unroll
                    for (int dx = 0; dx < 7; ++dx) {
                        const float s = v[1 + pp + dx];
                        const float t = fmaf(KC2, s, b2[pp].y);
                        const float w = fexp2(fmaf(s, t, cb2[pp].y + SARG(6, dx)));
                        num2[pp].y = fmaf(w, s, num2[pp].y);
                        den2[pp].y += w;
                    }
            } else {                         // packed pair: dy0 = rr, dy1 = rr-1
                #pragma unroll
                for (int pp = 0; pp < 4; ++pp)
                    #pragma unroll
                    for (int dx = 0; dx < 7; ++dx) {
                        const float s = v[1 + pp + dx];
                        const v2f s2 = {s, s};
                        const v2f c2 = cb2[pp] + (v2f){SARG(rr, dx), SARG(rr - 1, dx)};
                        const v2f t2 = __builtin_elementwise_fma(KC2v, s2, b2[pp]);
                        const v2f a2 = __builtin_elementwise_fma(s2, t2, c2);
                        const v2f w2 = {fexp2(a2.x), fexp2(a2.y)};
                        num2[pp] = __builtin_elementwise_fma(w2, s2, num2[pp]);
                        den2[pp] = den2[pp] + w2;
                    }
            }
        }

        v4f o0, o1;
        #pragma unroll
        for (int pp = 0; pp < 4; ++pp) {
            o0[pp] = num2[pp].x * __builtin_amdgcn_rcpf(den2[pp].x);
            o1[pp] = num2[pp].y * __builtin_amdgcn_rcpf(den2[pp].y);
        }
        float* q0 = q + (size_t)(gy0 + ory) * W + gx0 + 4 * tx;
        *reinterpret_cast<v4f*>(q0)     = o0;
        *reinterpret_cast<v4f*>(q0 + W) = o1;
    }
}

extern "C" void kernel_launch(void* const* d_in, const int* in_sizes, int n_in,
                              void* d_out, int out_size, void* d_ws, size_t ws_size,
                              hipStream_t stream)
{
    const float* in = (const float*)d_in[0];
    float* out = (float*)d_out;

    const int H = 1024, W = 1024;
    const int planes = in_sizes[0] / (H * W);       // 48

    dim3 grid(W / TW, H / TH, planes);              // 4 x 64 x 48
    dim3 block(64, 4, 1);
    bilateral_kernel<<<grid, block, 0, stream>>>(in, out, H, W);
}